// Round 12
// baseline (4271.035 us; speedup 1.0000x reference)
//
#include <hip/hip_runtime.h>
#include <hip/hip_bf16.h>

// LSTM (B=64,T=512,I=512,H=1024,O=1), 2 layers + sigmoid head.
// R12 = R11 + (a) fragment-order LDS for W (zero bank conflicts, no XOR) and
//             (b) 8-leader release-line barrier (kills the 32-line poll storm).
//  - Layer-pipelined: WGs 0..127 layer0, 128..255 layer1, skew 2; 514 phases.
//  - Operand swap: A = W rows (unit-major) from LDS fragments, B = h/x.
//    Lane holds all 4 gates (regs) of unit (j0 + rt*4 + lane>>4) for batch
//    (wave*16 + lane&15): zero-shuffle elementwise.
//  - Fragment-order LDS: A-fragment for (row-tile rt, k-tile kk) lives at
//    slot ((rt*NK+kk)*64+lane)*16B -> each wave read is 64 consecutive 16B,
//    conflict-free by construction.
//  - Barrier: 32 arrive lines (8 WGs each, RELAXED RMW after vmcnt-draining
//    __syncthreads). Leaders (wg<8) poll the 32 lines, post phase p to
//    release line wg; followers poll release line (wg&7) only.
//  - h protocol (R8): sc0sc1 u64 write-through stores, plain cached reads of
//    per-step FRESH slabs in REVERSE address order; no fences except a
//    workgroup-scope acquire (s_waitcnt only) after the wait.

namespace {

constexpr int B_ = 64, T_ = 512, I_ = 512, H_ = 1024;
constexpr int NWG = 256, NTHR = 256;
constexpr int BH = B_ * H_;

typedef __attribute__((ext_vector_type(8))) short short8;
typedef __attribute__((ext_vector_type(4))) float f32x4;

#define MFMA16(a, b, c) __builtin_amdgcn_mfma_f32_16x16x32_bf16((a), (b), (c), 0, 0, 0)

__device__ __forceinline__ float sigm(float x)  { return 1.f / (1.f + __expf(-x)); }
__device__ __forceinline__ float tanhx(float x) { return 2.f / (1.f + __expf(-2.f * x)) - 1.f; }

__device__ __forceinline__ unsigned f2bf(float f) {
  unsigned u = __float_as_uint(f);
  unsigned rnd = 0x7FFFu + ((u >> 16) & 1u);
  return (u + rnd) >> 16;   // low 16 bits valid
}
__device__ __forceinline__ float bf2f(unsigned short s) {
  return __uint_as_float(((unsigned)s) << 16);
}

__global__ void cvt_bf16_k(const float* __restrict__ src, unsigned short* __restrict__ dst, int n4) {
  int i = blockIdx.x * 256 + threadIdx.x;
  if (i >= n4) return;
  float4 v = reinterpret_cast<const float4*>(src)[i];
  ushort4 o;
  o.x = (unsigned short)f2bf(v.x); o.y = (unsigned short)f2bf(v.y);
  o.z = (unsigned short)f2bf(v.z); o.w = (unsigned short)f2bf(v.w);
  reinterpret_cast<ushort4*>(dst)[i] = o;
}

// zero slab-0 of both records (at REVERSED position T_) and the barrier region
__global__ void zero_init_k(unsigned short* __restrict__ h1, unsigned short* __restrict__ h2,
                            unsigned* __restrict__ bar) {
  int i = blockIdx.x * 256 + threadIdx.x;
  if (i < BH) h1[(size_t)T_ * BH + i] = 0;
  if (i < BH) h2[(size_t)T_ * BH + i] = 0;
  if (i < 2048) bar[i] = 0;   // 32 arrive lines + 8 release lines (stride 32)
}

// bars: arrive line g at bars[g*32] (g<32; 8 WGs each; monotonic: after all
// arrivals of phase p each == 8*(p+1)). Release line r at bars[1024+r*32]
// (r<8): leader wg==r stores the latest completed-wait phase p.
// Records: slab s at rec + (T_-s)*BH (reverse order). Step t: read slab t,
// write slab t+1. Layer1 input for step t = h1 slab t+1.
__global__ __launch_bounds__(NTHR, 1) void lstm_fused(
    const unsigned short* __restrict__ xb,
    const unsigned short* __restrict__ wih0, const unsigned short* __restrict__ whh0,
    const float* __restrict__ bih0, const float* __restrict__ bhh0,
    const unsigned short* __restrict__ wih1, const unsigned short* __restrict__ whh1,
    const float* __restrict__ bih1, const float* __restrict__ bhh1,
    unsigned short* __restrict__ h1rec, unsigned short* __restrict__ h2rec,
    unsigned* __restrict__ bars)
{
  // fragment-order W storage: slot ((rt*NK+kk)*64+lane) holds 8 shorts =
  // row (rt*16 + lane&15), shorts [ (lane>>4)*8 + kk*32 , +8 )
  __shared__ unsigned short s_win[32768];   // 64 KB (layer0 uses half)
  __shared__ unsigned short s_whh[32768];   // 64 KB

  const int tid   = threadIdx.x;
  const int wg    = blockIdx.x;       // 0..255
  const int layer = wg >> 7;          // 0..1
  const int lwg   = wg & 127;
  const int wave  = tid >> 6;         // 0..3 -> batch tile
  const int lane  = tid & 63;
  const int j0    = lwg * 8;          // first of 8 hidden units owned
  const int n     = lane & 15;
  const int u4    = lane >> 4;        // k-group / unit offset in ew
  const int k0    = u4 * 8;
  const int arow  = wave * 16 + n;    // batch row for B fragments

  const unsigned short* w_in = layer ? wih1 : wih0;
  const unsigned short* w_hh = layer ? whh1 : whh0;
  const float* b_i = layer ? bih1 : bih0;
  const float* b_h = layer ? bhh1 : bhh0;
  unsigned short* rec = layer ? h2rec : h1rec;
  const int K_IN = layer ? 1024 : 512;
  const int NKI  = K_IN / 32;         // in-GEMM k-tiles (16 or 32)

  unsigned* grp = bars + (wg >> 3) * 32;
  unsigned* rel = bars + 1024 + (wg & 7) * 32;

  // ---- stage W into fragment-order LDS ----
  // c = (rt*NK + kk)*64 + l ; row rr = l&15, k-group q = l>>4
  for (int c = tid; c < 2 * NKI * 64; c += NTHR) {
    int l  = c & 63;
    int kk = (c >> 6) % NKI;
    int rt = c / (NKI * 64);
    int rr = l & 15, q = l >> 4;
    int grow = (rr & 3) * H_ + j0 + rt * 4 + (rr >> 2);
    *reinterpret_cast<short8*>(&s_win[c * 8]) =
        *reinterpret_cast<const short8*>(&w_in[(size_t)grow * K_IN + kk * 32 + q * 8]);
  }
  for (int c = tid; c < 2 * 32 * 64; c += NTHR) {
    int l  = c & 63;
    int kk = (c >> 6) & 31;
    int rt = c >> 11;
    int rr = l & 15, q = l >> 4;
    int grow = (rr & 3) * H_ + j0 + rt * 4 + (rr >> 2);
    *reinterpret_cast<short8*>(&s_whh[c * 8]) =
        *reinterpret_cast<const short8*>(&w_hh[(size_t)grow * H_ + kk * 32 + q * 8]);
  }
  float bias0[4], bias1[4];
  #pragma unroll
  for (int g = 0; g < 4; ++g) {
    bias0[g] = b_i[g * H_ + j0 + u4]     + b_h[g * H_ + j0 + u4];
    bias1[g] = b_i[g * H_ + j0 + 4 + u4] + b_h[g * H_ + j0 + 4 + u4];
  }
  __syncthreads();

  float cst0 = 0.f, cst1 = 0.f;
  f32x4 na0 = {0.f, 0.f, 0.f, 0.f}, na1 = {0.f, 0.f, 0.f, 0.f};

  // prologue: layer0's in-acc for step 0
  if (layer == 0) {
    const unsigned short* a_in = xb + (size_t)arow * (T_ * I_) + k0;
    #pragma unroll
    for (int kk = 0; kk < 16; ++kk) {
      short8 bv = *reinterpret_cast<const short8*>(a_in + kk * 32);
      na0 = MFMA16(*reinterpret_cast<const short8*>(&s_win[(kk * 64 + lane) * 8]),          bv, na0);
      na1 = MFMA16(*reinterpret_cast<const short8*>(&s_win[((16 + kk) * 64 + lane) * 8]),   bv, na1);
    }
  }

  for (int p = 0; p <= T_ + 1; ++p) {
    // ---- wait for phase p ----
    if (p > 0) {
      const unsigned tgt = (unsigned)p * 8u;
      if (wg < 8) {
        if (wave == 0) {
          for (;;) {
            unsigned v = 0xFFFFFFFFu;
            if (lane < 32)
              v = __hip_atomic_load(bars + lane * 32, __ATOMIC_RELAXED, __HIP_MEMORY_SCOPE_AGENT);
            if (__all((int)(lane >= 32 || v >= tgt))) break;
            __builtin_amdgcn_s_sleep(1);
          }
          if (lane == 0)
            __hip_atomic_store(rel, (unsigned)p, __ATOMIC_RELAXED, __HIP_MEMORY_SCOPE_AGENT);
        } else {
          while (__hip_atomic_load(rel, __ATOMIC_RELAXED, __HIP_MEMORY_SCOPE_AGENT) < (unsigned)p)
            __builtin_amdgcn_s_sleep(1);
        }
      } else {
        while (__hip_atomic_load(rel, __ATOMIC_RELAXED, __HIP_MEMORY_SCOPE_AGENT) < (unsigned)p)
          __builtin_amdgcn_s_sleep(1);
      }
      __builtin_amdgcn_fence(__ATOMIC_ACQUIRE, "workgroup");  // ordering only, no cache ops
    }

    f32x4 acc0 = na0, acc1 = na1;
    const int t = layer ? p - 2 : p;

    if (t >= 0 && t < T_) {
      // ---- hh GEMM: B = h[slab t] (cached), A = s_whh fragments ----
      const unsigned short* a_h = rec + (size_t)(T_ - t) * BH + (size_t)arow * H_ + k0;
      short8 hf[32];
      #pragma unroll
      for (int kk = 0; kk < 32; ++kk)
        hf[kk] = *reinterpret_cast<const short8*>(a_h + kk * 32);
      #pragma unroll
      for (int kk = 0; kk < 32; ++kk) {
        acc0 = MFMA16(*reinterpret_cast<const short8*>(&s_whh[(kk * 64 + lane) * 8]),        hf[kk], acc0);
        acc1 = MFMA16(*reinterpret_cast<const short8*>(&s_whh[((32 + kk) * 64 + lane) * 8]), hf[kk], acc1);
      }

      // ---- elementwise (zero-shuffle) ----
      float gi0 = sigm(acc0[0] + bias0[0]);
      float gf0 = sigm(acc0[1] + bias0[1]);
      float gg0 = tanhx(acc0[2] + bias0[2]);
      float go0 = sigm(acc0[3] + bias0[3]);
      cst0 = gf0 * cst0 + gi0 * gg0;
      float hv0 = go0 * tanhx(cst0);

      float gi1 = sigm(acc1[0] + bias1[0]);
      float gf1 = sigm(acc1[1] + bias1[1]);
      float gg1 = tanhx(acc1[2] + bias1[2]);
      float go1 = sigm(acc1[3] + bias1[3]);
      cst1 = gf1 * cst1 + gi1 * gg1;
      float hv1 = go1 * tanhx(cst1);

      unsigned a16 = f2bf(hv0) & 0xFFFFu;
      unsigned b16 = f2bf(hv1) & 0xFFFFu;
      unsigned a1 = __shfl(a16, (lane & 15) | 16, 64);
      unsigned a2 = __shfl(a16, (lane & 15) | 32, 64);
      unsigned a3 = __shfl(a16, (lane & 15) | 48, 64);
      unsigned b1 = __shfl(b16, (lane & 15) | 16, 64);
      unsigned b2 = __shfl(b16, (lane & 15) | 32, 64);
      unsigned b3 = __shfl(b16, (lane & 15) | 48, 64);
      if (lane < 16) {
        unsigned long long qa = (unsigned long long)(a16 | (a1 << 16)) |
                                ((unsigned long long)(a2 | (a3 << 16)) << 32);
        unsigned long long qb = (unsigned long long)(b16 | (b1 << 16)) |
                                ((unsigned long long)(b2 | (b3 << 16)) << 32);
        unsigned long long* dst = (unsigned long long*)
            (rec + (size_t)(T_ - t - 1) * BH + (size_t)(wave * 16 + lane) * H_ + j0);
        __hip_atomic_store(dst,     qa, __ATOMIC_RELAXED, __HIP_MEMORY_SCOPE_AGENT);
        __hip_atomic_store(dst + 1, qb, __ATOMIC_RELAXED, __HIP_MEMORY_SCOPE_AGENT);
      }
    }

    // ---- arrive: __syncthreads drains vmcnt(0) => stores ack'd at MALL ----
    __syncthreads();
    if (tid == 0)
      __hip_atomic_fetch_add(grp, 1u, __ATOMIC_RELAXED, __HIP_MEMORY_SCOPE_AGENT);

    // ---- shadow: in-GEMM for this WG's next step (input sealed by wait) ----
    na0 = (f32x4){0.f, 0.f, 0.f, 0.f};
    na1 = (f32x4){0.f, 0.f, 0.f, 0.f};
    const int tn = layer ? p - 1 : p + 1;
    if (tn >= 0 && tn < T_) {
      if (layer == 0) {
        const unsigned short* a_in = xb + (size_t)arow * (T_ * I_) + (size_t)tn * I_ + k0;
        #pragma unroll
        for (int kk = 0; kk < 16; ++kk) {
          short8 bv = *reinterpret_cast<const short8*>(a_in + kk * 32);
          na0 = MFMA16(*reinterpret_cast<const short8*>(&s_win[(kk * 64 + lane) * 8]),        bv, na0);
          na1 = MFMA16(*reinterpret_cast<const short8*>(&s_win[((16 + kk) * 64 + lane) * 8]), bv, na1);
        }
      } else {
        // input = h1 slab tn+1, written phase tn (= p-1), sealed by wait(p)
        const unsigned short* a_in = h1rec + (size_t)(T_ - 1 - tn) * BH + (size_t)arow * H_ + k0;
        #pragma unroll
        for (int kk = 0; kk < 32; ++kk) {
          short8 bv = *reinterpret_cast<const short8*>(a_in + kk * 32);
          na0 = MFMA16(*reinterpret_cast<const short8*>(&s_win[(kk * 64 + lane) * 8]),        bv, na0);
          na1 = MFMA16(*reinterpret_cast<const short8*>(&s_win[((32 + kk) * 64 + lane) * 8]), bv, na1);
        }
      }
    }
  }
}

__global__ void out_head(const unsigned short* __restrict__ h2,
                         const float* __restrict__ W_out,
                         const float* __restrict__ b_out,
                         float* __restrict__ out) {
  int b = blockIdx.x;      // 64
  int lane = threadIdx.x;  // 64 (one wave)
  float s = 0.f;
  for (int k = lane; k < H_; k += 64)
    s += bf2f(h2[(size_t)b * H_ + k]) * W_out[k];
  #pragma unroll
  for (int off = 32; off; off >>= 1) s += __shfl_down(s, off, 64);
  if (lane == 0) out[b] = sigm(s + b_out[0]);
}

} // namespace

extern "C" void kernel_launch(void* const* d_in, const int* in_sizes, int n_in,
                              void* d_out, int out_size, void* d_ws, size_t ws_size,
                              hipStream_t stream) {
  const float* x    = (const float*)d_in[0];
  const float* Wih0 = (const float*)d_in[1];
  const float* Whh0 = (const float*)d_in[2];
  const float* bih0 = (const float*)d_in[3];
  const float* bhh0 = (const float*)d_in[4];
  const float* Wih1 = (const float*)d_in[5];
  const float* Whh1 = (const float*)d_in[6];
  const float* bih1 = (const float*)d_in[7];
  const float* bhh1 = (const float*)d_in[8];
  const float* Wout = (const float*)d_in[9];
  const float* bout = (const float*)d_in[10];
  float* out = (float*)d_out;

  char* ws = (char*)d_ws;
  size_t off = 0;
  auto alloc = [&](size_t bytes) -> char* {
    char* p = ws + off;
    off += (bytes + 4095) & ~(size_t)4095;   // 4KB-align every region
    return p;
  };
  const size_t REC = (size_t)(T_ + 1) * BH * 2;       // 67.2 MB (513 slabs)

  unsigned* bar        = (unsigned*)alloc(8192);      // 2048 u32: arrive+release
  unsigned short* xb   = (unsigned short*)alloc((size_t)B_ * T_ * I_ * 2);
  unsigned short* wih0 = (unsigned short*)alloc((size_t)4 * H_ * I_ * 2);
  unsigned short* whh0 = (unsigned short*)alloc((size_t)4 * H_ * H_ * 2);
  unsigned short* wih1 = (unsigned short*)alloc((size_t)4 * H_ * H_ * 2);
  unsigned short* whh1 = (unsigned short*)alloc((size_t)4 * H_ * H_ * 2);
  unsigned short* h1   = (unsigned short*)alloc(REC);
  unsigned short* h2   = (unsigned short*)alloc(REC);

  auto cvt = [&](const float* s, unsigned short* d, int nelem) {
    int n4 = nelem / 4;
    cvt_bf16_k<<<(n4 + 255) / 256, 256, 0, stream>>>(s, d, n4);
  };
  cvt(x,    xb,   B_ * T_ * I_);
  cvt(Wih0, wih0, 4 * H_ * I_);
  cvt(Whh0, whh0, 4 * H_ * H_);
  cvt(Wih1, wih1, 4 * H_ * H_);
  cvt(Whh1, whh1, 4 * H_ * H_);
  zero_init_k<<<(BH + 255) / 256, 256, 0, stream>>>(h1, h2, bar);

  lstm_fused<<<NWG, NTHR, 0, stream>>>(
      xb, wih0, whh0, bih0, bhh0, wih1, whh1, bih1, bhh1, h1, h2, bar);

  // final h2 = layer1 step 511 output = slab 512 -> reversed offset 0
  out_head<<<B_, 64, 0, stream>>>(h2, Wout, bout, out);
}